// Round 1
// baseline (603.261 us; speedup 1.0000x reference)
//
#include <hip/hip_runtime.h>
#include <hip/hip_bf16.h>

// Problem: B=64, T=2048, D=784, N1=100, N2=10, dt=0.04
//   z1 = batch @ W1^T          (fp32 GEMM, M=131072 K=784 N=100->padded 128)
//   V1 = FHN scan over T       (sequential in t, parallel over 64*100 lanes)
//   z2 = (0.5*V1) @ W2^T       (tiny GEMM)
//   V2 = FHN scan -> output    (64*10 lanes)
//
// Workspace layout (floats), time-chunked with chunk TC (divisor of 2048):
//   W1t   : 784*128                   (padded transpose of W1)
//   z1p   : 64*TC*128
//   V1    : 64*TC*100
//   z2    : 64*TC*10
//   carry : 64*100 (V1) + 64*100 (S1) + 64*10 (V2) + 64*10 (S2) = 14080

#define FHN_DT 0.04f

__global__ void prep_w1t_kernel(const float* __restrict__ W1, float* __restrict__ W1t) {
    int idx = blockIdx.x * 256 + threadIdx.x;   // < 784*128
    int k = idx >> 7, n = idx & 127;
    if (k < 784) W1t[idx] = (n < 100) ? W1[n * 784 + k] : 0.0f;
}

__global__ void init_carry_kernel(float* __restrict__ c) {
    int i = blockIdx.x * 256 + threadIdx.x;
    if (i < 14080) c[i] = 0.0f;
}

// ---------------- GEMM1: z1p[row][0..127] = batch[row][:] . W1t[:][c] ----------------
// 128x128 tile per block, 256 threads, 8x8 register tile, KC=16.
__global__ __launch_bounds__(256) void gemm1_kernel(const float* __restrict__ A,
                                                    const float* __restrict__ W1t,
                                                    float* __restrict__ z1p,
                                                    int t0, int TC) {
    __shared__ __align__(16) float As[16][132];      // [k][row], padded stride
    __shared__ __align__(16) float Wls[16 * 128];    // [k][col], XOR-swizzled

    int tid = threadIdx.x;
    int spb = TC >> 7;                   // 128-row sub-blocks per batch-chunk
    int bb  = blockIdx.x / spb;
    int sub = blockIdx.x % spb;
    long row_g0 = (long)bb * 2048 + t0 + sub * 128;   // global batch row
    long row_l0 = (long)bb * TC + sub * 128;          // chunk-local row
    int tx = tid & 15, ty = tid >> 4;

    float acc[8][8] = {};

    for (int k0 = 0; k0 < 784; k0 += 16) {
        // stage A tile (128 rows x 16 k), transposed into As[k][row]
#pragma unroll
        for (int l = 0; l < 2; l++) {
            int fid  = tid + l * 256;          // 0..511
            int row  = fid >> 2;
            int quad = fid & 3;
            const float4 av = *(const float4*)(A + (row_g0 + row) * 784 + k0 + quad * 4);
            As[quad * 4 + 0][row] = av.x;
            As[quad * 4 + 1][row] = av.y;
            As[quad * 4 + 2][row] = av.z;
            As[quad * 4 + 3][row] = av.w;
        }
        // stage W tile (16 k x 128 cols), XOR-swizzle bit2 by bit5 to kill 4-way conflicts
#pragma unroll
        for (int l = 0; l < 2; l++) {
            int fid  = tid + l * 256;
            int krow = fid >> 5;
            int c    = (fid & 31) * 4;
            int phys = c ^ ((((unsigned)c >> 5) & 1) << 2);
            *(float4*)&Wls[krow * 128 + phys] = *(const float4*)(W1t + (k0 + krow) * 128 + c);
        }
        __syncthreads();

#pragma unroll
        for (int k = 0; k < 16; k++) {
            float4 a0 = *(float4*)&As[k][ty * 8];
            float4 a1 = *(float4*)&As[k][ty * 8 + 4];
            int c0 = tx * 8;
            int c1 = tx * 8 + 4;
            int p0 = c0 ^ ((((unsigned)c0 >> 5) & 1) << 2);
            int p1 = c1 ^ ((((unsigned)c1 >> 5) & 1) << 2);
            float4 b0 = *(float4*)&Wls[k * 128 + p0];
            float4 b1 = *(float4*)&Wls[k * 128 + p1];
            float ra[8] = {a0.x, a0.y, a0.z, a0.w, a1.x, a1.y, a1.z, a1.w};
            float rb[8] = {b0.x, b0.y, b0.z, b0.w, b1.x, b1.y, b1.z, b1.w};
#pragma unroll
            for (int i = 0; i < 8; i++) {
#pragma unroll
                for (int j = 0; j < 8; j++) acc[i][j] += ra[i] * rb[j];
            }
        }
        __syncthreads();
    }

#pragma unroll
    for (int i = 0; i < 8; i++) {
        long row_l = row_l0 + ty * 8 + i;
        float4 v0 = make_float4(acc[i][0], acc[i][1], acc[i][2], acc[i][3]);
        float4 v1 = make_float4(acc[i][4], acc[i][5], acc[i][6], acc[i][7]);
        *(float4*)(z1p + row_l * 128 + tx * 8)     = v0;
        *(float4*)(z1p + row_l * 128 + tx * 8 + 4) = v1;
    }
}

// ---------------- scan1: FHN over time, 64 blocks x (100 active lanes) ----------------
__global__ void scan1_kernel(const float* __restrict__ z1p, float* __restrict__ V1,
                             float* __restrict__ carry, int TC) {
    int b = blockIdx.x;
    int n = threadIdx.x;
    if (n >= 100) return;
    const float dt = FHN_DT;
    float V = carry[b * 100 + n];
    float S = carry[6400 + b * 100 + n];
    const float* zb = z1p + (long)b * TC * 128 + n;
    float* vb = V1 + (long)b * TC * 100 + n;

    float zc[16], zn[16];
#pragma unroll
    for (int u = 0; u < 16; u++) zc[u] = zb[u * 128];

    for (int tt0 = 0; tt0 < TC; tt0 += 16) {
        if (tt0 + 16 < TC) {
#pragma unroll
            for (int u = 0; u < 16; u++) zn[u] = zb[(tt0 + 16 + u) * 128];
        }
#pragma unroll
        for (int u = 0; u < 16; u++) {
            vb[(tt0 + u) * 100] = V;
            float z  = zc[u];
            float Vn = (1.0f + dt) * V - (dt / 3.0f) * (V * V * V) - dt * S + dt * z;
            float Sn = S + dt * 0.08f * (V + 0.7f - 0.8f * S);
            V = Vn;
            S = Sn;
        }
#pragma unroll
        for (int u = 0; u < 16; u++) zc[u] = zn[u];
    }
    carry[b * 100 + n] = V;
    carry[6400 + b * 100 + n] = S;
}

// ---------------- GEMM2: z2[row][m] = 0.5 * V1[row][:] . W2[m][:] ----------------
__global__ __launch_bounds__(256) void gemm2_kernel(const float* __restrict__ V1,
                                                    const float* __restrict__ W2,
                                                    float* __restrict__ z2, int TC) {
    __shared__ float V1s[6400];   // 64 rows x 100
    __shared__ float W2s[1000];   // 10 x 100
    long row0 = (long)blockIdx.x * 64;
    int tid = threadIdx.x;
    for (int i = tid; i < 6400; i += 256) V1s[i] = V1[row0 * 100 + i];
    for (int i = tid; i < 1000; i += 256) W2s[i] = W2[i];
    __syncthreads();
    for (int o = tid; o < 640; o += 256) {
        int r = o / 10, m = o % 10;
        float acc = 0.0f;
#pragma unroll 4
        for (int k = 0; k < 100; k++) acc += V1s[r * 100 + k] * W2s[m * 100 + k];
        z2[(row0 + r) * 10 + m] = 0.5f * acc;
    }
}

// ---------------- scan2: FHN over time, 640 lanes, writes d_out ----------------
__global__ void scan2_kernel(const float* __restrict__ z2, float* __restrict__ out,
                             float* __restrict__ carry, int t0, int TC) {
    int g = blockIdx.x * 64 + threadIdx.x;   // 0..639
    if (g >= 640) return;
    int b = g / 10, m = g % 10;
    const float dt = FHN_DT;
    float V = carry[12800 + g];
    float S = carry[13440 + g];
    const float* zb = z2 + (long)b * TC * 10 + m;
    float* ob = out + ((long)b * 2048 + t0) * 10 + m;

    float zc[16], zn[16];
#pragma unroll
    for (int u = 0; u < 16; u++) zc[u] = zb[u * 10];

    for (int tt0 = 0; tt0 < TC; tt0 += 16) {
        if (tt0 + 16 < TC) {
#pragma unroll
            for (int u = 0; u < 16; u++) zn[u] = zb[(tt0 + 16 + u) * 10];
        }
#pragma unroll
        for (int u = 0; u < 16; u++) {
            ob[(tt0 + u) * 10] = V;
            float z  = zc[u];
            float Vn = (1.0f + dt) * V - (dt / 3.0f) * (V * V * V) - dt * S + dt * z;
            float Sn = S + dt * 0.08f * (V + 0.7f - 0.8f * S);
            V = Vn;
            S = Sn;
        }
#pragma unroll
        for (int u = 0; u < 16; u++) zc[u] = zn[u];
    }
    carry[12800 + g] = V;
    carry[13440 + g] = S;
}

extern "C" void kernel_launch(void* const* d_in, const int* in_sizes, int n_in,
                              void* d_out, int out_size, void* d_ws, size_t ws_size,
                              hipStream_t stream) {
    const float* batch = (const float*)d_in[0];   // 64*2048*784
    const float* W1    = (const float*)d_in[1];   // 100*784
    const float* W2    = (const float*)d_in[2];   // 10*100
    float* out = (float*)d_out;                   // 64*2048*10
    float* ws  = (float*)d_ws;

    size_t ws_floats = ws_size / sizeof(float);

    // pick the largest time-chunk that fits the workspace
    int TC = 128;
    const int cands[4] = {2048, 1024, 512, 256};
    for (int i = 0; i < 4; i++) {
        size_t need = 114432 + (size_t)15232 * cands[i];  // W1t + carries + 64*TC*(128+100+10)
        if (need <= ws_floats) { TC = cands[i]; break; }
    }

    size_t oW1t = 0;
    size_t oZ1  = oW1t + 784 * 128;
    size_t oV1  = oZ1 + (size_t)64 * TC * 128;
    size_t oZ2  = oV1 + (size_t)64 * TC * 100;
    size_t oCar = oZ2 + (size_t)64 * TC * 10;

    prep_w1t_kernel<<<392, 256, 0, stream>>>(W1, ws + oW1t);
    init_carry_kernel<<<55, 256, 0, stream>>>(ws + oCar);

    int nchunks = 2048 / TC;
    for (int c = 0; c < nchunks; c++) {
        int t0 = c * TC;
        gemm1_kernel<<<64 * (TC / 128), 256, 0, stream>>>(batch, ws + oW1t, ws + oZ1, t0, TC);
        scan1_kernel<<<64, 128, 0, stream>>>(ws + oZ1, ws + oV1, ws + oCar, TC);
        gemm2_kernel<<<TC, 256, 0, stream>>>(ws + oV1, W2, ws + oZ2, TC);
        scan2_kernel<<<10, 64, 0, stream>>>(ws + oZ2, out, ws + oCar, t0, TC);
    }
}

// Round 2
// 387.544 us; speedup vs baseline: 1.5566x; 1.5566x over previous
//
#include <hip/hip_runtime.h>
#include <hip/hip_bf16.h>

// B=64, T=2048, D=784, N1=100, N2=10, dt=0.04
// Pipeline: gemm1 (bf16 split MFMA) -> scan1 -> gemm2 (fp32, sgpr W2) -> scan2
//
// ws layout (bytes):
//   Whi  : 112*800 ushort = 179200      (bf16 hi of W1, padded n->112, k->800)
//   Wlo  : 179200
//   z1p  : 131072*100 f32 = 52428800
//   V1   : 52428800
//   z2   : 131072*10 f32  = 5242880
// total ~105 MB (ws proven >=125 MB by round-1 run)

#define FHN_DT 0.04f

typedef __attribute__((ext_vector_type(8))) short     bf16x8;
typedef __attribute__((ext_vector_type(4))) float     f32x4;
typedef __attribute__((ext_vector_type(8))) unsigned short ushort8;

__device__ __forceinline__ unsigned short f2bf(float x) {
    unsigned u = __float_as_uint(x);
    u += 0x7fffu + ((u >> 16) & 1u);      // round-to-nearest-even
    return (unsigned short)(u >> 16);
}
__device__ __forceinline__ float bf2f(unsigned short h) {
    return __uint_as_float(((unsigned)h) << 16);
}

// ---------- prep: split W1 (100x784) into bf16 hi/lo, padded to 112x800 ----------
__global__ void prep_w_kernel(const float* __restrict__ W1,
                              unsigned short* __restrict__ Whi,
                              unsigned short* __restrict__ Wlo) {
    int idx = blockIdx.x * 256 + threadIdx.x;     // < 112*800 = 89600
    int n = idx / 800, k = idx % 800;
    float v = (n < 100 && k < 784) ? W1[n * 784 + k] : 0.0f;
    unsigned short h = f2bf(v);
    Whi[idx] = h;
    Wlo[idx] = f2bf(v - bf2f(h));
}

// ---------- GEMM1: z1p[row][n<100] = batch[row][:784] . W1[n][:784] ----------
// BM=256 rows/block, BN=112 (7 col-tiles of 16), BK=32, 4 waves, mfma 16x16x32 bf16,
// 3-term split: hi*hi + lo*hi + hi*lo, fp32 accumulate.
// LDS rows padded to 80 B (40 bf16) -> <=2-way bank aliasing on ds_read_b128.
#define LDSA_HI 0
#define LDSA_LO (256 * 80)            // 20480
#define LDSW_HI (2 * 256 * 80)        // 40960
#define LDSW_LO (LDSW_HI + 112 * 80)  // 49920
#define LDS_TOT (LDSW_LO + 112 * 80)  // 58880

__global__ __launch_bounds__(256, 2) void gemm1_mfma(const float* __restrict__ A,
                                                     const unsigned short* __restrict__ Whi,
                                                     const unsigned short* __restrict__ Wlo,
                                                     float* __restrict__ z1p) {
    __shared__ __align__(16) char smem[LDS_TOT];
    const int tid  = threadIdx.x;
    const int w    = tid >> 6;
    const int lane = tid & 63;
    const long row0 = (long)blockIdx.x * 256;

    f32x4 acc[4][7] = {};

    for (int k0 = 0; k0 < 800; k0 += 32) {
        // ---- stage A tile 256x32 fp32 -> bf16 hi/lo in LDS ----
#pragma unroll
        for (int l = 0; l < 8; l++) {
            int fid  = l * 256 + tid;           // 0..2047
            int row  = fid >> 3;
            int quad = fid & 7;
            int kg   = k0 + quad * 4;
            float4 av = make_float4(0.f, 0.f, 0.f, 0.f);
            if (kg < 784) av = *(const float4*)(A + (row0 + row) * 784 + kg);
            ushort4 hv, lv;
            hv.x = f2bf(av.x); lv.x = f2bf(av.x - bf2f(hv.x));
            hv.y = f2bf(av.y); lv.y = f2bf(av.y - bf2f(hv.y));
            hv.z = f2bf(av.z); lv.z = f2bf(av.z - bf2f(hv.z));
            hv.w = f2bf(av.w); lv.w = f2bf(av.w - bf2f(hv.w));
            char* d = smem + row * 80 + quad * 8;
            *(ushort4*)(d + LDSA_HI) = hv;
            *(ushort4*)(d + LDSA_LO) = lv;
        }
        // ---- stage W tile 112x32 hi+lo (already bf16 in global) ----
#pragma unroll
        for (int l = 0; l < 4; l++) {
            int fid = l * 256 + tid;            // 0..1023, need 896
            if (fid < 896) {
                int isHi = fid < 448;
                int u = isHi ? fid : fid - 448;
                int n = u >> 2, q = u & 3;
                const unsigned short* src = (isHi ? Whi : Wlo) + n * 800 + k0 + q * 8;
                ushort8 wv = *(const ushort8*)src;
                *(ushort8*)(smem + (isHi ? LDSW_HI : LDSW_LO) + n * 80 + q * 16) = wv;
            }
        }
        __syncthreads();

        // ---- compute: 4 row-tiles x 7 col-tiles x 3 splits ----
        const int ln = lane & 15;
        const int kb = (lane >> 4) * 16;        // byte offset of this lane's k-slice
        bf16x8 ah[4], al[4];
#pragma unroll
        for (int rt = 0; rt < 4; rt++) {
            int row = w * 64 + rt * 16 + ln;
            ah[rt] = *(const bf16x8*)(smem + LDSA_HI + row * 80 + kb);
            al[rt] = *(const bf16x8*)(smem + LDSA_LO + row * 80 + kb);
        }
#pragma unroll
        for (int ct = 0; ct < 7; ct++) {
            int n = ct * 16 + ln;
            bf16x8 bh = *(const bf16x8*)(smem + LDSW_HI + n * 80 + kb);
            bf16x8 bl = *(const bf16x8*)(smem + LDSW_LO + n * 80 + kb);
#pragma unroll
            for (int rt = 0; rt < 4; rt++) {
                acc[rt][ct] = __builtin_amdgcn_mfma_f32_16x16x32_bf16(ah[rt], bh, acc[rt][ct], 0, 0, 0);
                acc[rt][ct] = __builtin_amdgcn_mfma_f32_16x16x32_bf16(al[rt], bh, acc[rt][ct], 0, 0, 0);
                acc[rt][ct] = __builtin_amdgcn_mfma_f32_16x16x32_bf16(ah[rt], bl, acc[rt][ct], 0, 0, 0);
            }
        }
        __syncthreads();
    }

    // ---- epilogue: D col = lane&15, row = (lane>>4)*4 + r ----
    const int ln = lane & 15, lg = lane >> 4;
#pragma unroll
    for (int ct = 0; ct < 7; ct++) {
        int n = ct * 16 + ln;
        if (n < 100) {
#pragma unroll
            for (int rt = 0; rt < 4; rt++) {
                long row_g = row0 + w * 64 + rt * 16 + lg * 4;
                float* p = z1p + row_g * 100 + n;
#pragma unroll
                for (int r = 0; r < 4; r++) p[r * 100] = acc[rt][ct][r];
            }
        }
    }
}

// ---------- scan1: FHN over t, 64 blocks x 100 lanes ----------
__global__ void scan1_kernel(const float* __restrict__ z1p, float* __restrict__ V1) {
    int b = blockIdx.x;
    int n = threadIdx.x;
    if (n >= 100) return;
    const float dt = FHN_DT;
    float V = 0.0f, S = 0.0f;
    const float* zb = z1p + (long)b * 2048 * 100 + n;
    float* vb = V1 + (long)b * 2048 * 100 + n;

    float zc[16], zn[16];
#pragma unroll
    for (int u = 0; u < 16; u++) zc[u] = zb[u * 100];

    for (int t0 = 0; t0 < 2048; t0 += 16) {
        if (t0 + 16 < 2048) {
#pragma unroll
            for (int u = 0; u < 16; u++) zn[u] = zb[(t0 + 16 + u) * 100];
        }
#pragma unroll
        for (int u = 0; u < 16; u++) {
            vb[(t0 + u) * 100] = V;
            float z  = zc[u];
            float Vn = (1.0f + dt) * V - (dt / 3.0f) * (V * V * V) - dt * S + dt * z;
            float Sn = S + dt * 0.08f * (V + 0.7f - 0.8f * S);
            V = Vn;
            S = Sn;
        }
#pragma unroll
        for (int u = 0; u < 16; u++) zc[u] = zn[u];
    }
}

// ---------- GEMM2: z2[row][m] = 0.5 * V1[row][:100] . W2[m][:100], W2 via sgpr ----------
__global__ __launch_bounds__(256) void gemm2_kernel(const float* __restrict__ V1,
                                                    const float* __restrict__ W2,
                                                    float* __restrict__ z2) {
    long row = (long)blockIdx.x * 256 + threadIdx.x;   // grid 512 -> 131072 rows
    const float4* vr = (const float4*)(V1 + row * 100);
    float acc[10] = {};
    for (int kq = 0; kq < 25; kq++) {
        float4 v = vr[kq];
#pragma unroll
        for (int m = 0; m < 10; m++) {
            const float* wm = W2 + m * 100 + kq * 4;   // thread-uniform -> s_load
            acc[m] += v.x * wm[0] + v.y * wm[1] + v.z * wm[2] + v.w * wm[3];
        }
    }
    float* o = z2 + row * 10;
#pragma unroll
    for (int m = 0; m < 10; m++) o[m] = 0.5f * acc[m];
}

// ---------- scan2: FHN over t, 640 lanes, writes d_out ----------
__global__ void scan2_kernel(const float* __restrict__ z2, float* __restrict__ out) {
    int g = blockIdx.x * 64 + threadIdx.x;   // 0..639
    if (g >= 640) return;
    int b = g / 10, m = g % 10;
    const float dt = FHN_DT;
    float V = 0.0f, S = 0.0f;
    const float* zb = z2 + (long)b * 2048 * 10 + m;
    float* ob = out + (long)b * 2048 * 10 + m;

    float zc[16], zn[16];
#pragma unroll
    for (int u = 0; u < 16; u++) zc[u] = zb[u * 10];

    for (int t0 = 0; t0 < 2048; t0 += 16) {
        if (t0 + 16 < 2048) {
#pragma unroll
            for (int u = 0; u < 16; u++) zn[u] = zb[(t0 + 16 + u) * 10];
        }
#pragma unroll
        for (int u = 0; u < 16; u++) {
            ob[(t0 + u) * 10] = V;
            float z  = zc[u];
            float Vn = (1.0f + dt) * V - (dt / 3.0f) * (V * V * V) - dt * S + dt * z;
            float Sn = S + dt * 0.08f * (V + 0.7f - 0.8f * S);
            V = Vn;
            S = Sn;
        }
#pragma unroll
        for (int u = 0; u < 16; u++) zc[u] = zn[u];
    }
}

extern "C" void kernel_launch(void* const* d_in, const int* in_sizes, int n_in,
                              void* d_out, int out_size, void* d_ws, size_t ws_size,
                              hipStream_t stream) {
    const float* batch = (const float*)d_in[0];   // 64*2048*784
    const float* W1    = (const float*)d_in[1];   // 100*784
    const float* W2    = (const float*)d_in[2];   // 10*100
    float* out = (float*)d_out;                   // 64*2048*10

    char* base = (char*)d_ws;
    unsigned short* Whi = (unsigned short*)base;                  // 179200 B
    unsigned short* Wlo = (unsigned short*)(base + 179200);       // 179200 B
    float* z1p = (float*)(base + 358400);                         // 131072*100
    float* V1  = z1p + (size_t)131072 * 100;
    float* z2  = V1 + (size_t)131072 * 100;                       // 131072*10

    prep_w_kernel<<<350, 256, 0, stream>>>(W1, Whi, Wlo);
    gemm1_mfma<<<512, 256, 0, stream>>>(batch, Whi, Wlo, z1p);
    scan1_kernel<<<64, 128, 0, stream>>>(z1p, V1);
    gemm2_kernel<<<512, 256, 0, stream>>>(V1, W2, z2);
    scan2_kernel<<<10, 64, 0, stream>>>(z2, out);
}

// Round 3
// 360.135 us; speedup vs baseline: 1.6751x; 1.0761x over previous
//
#include <hip/hip_runtime.h>
#include <hip/hip_bf16.h>

// B=64, T=2048, D=784, N1=100, N2=10, dt=0.04
// Pipeline:
//   prep_w6     : W1 -> exact 3x bf16 split (h/m/l), pre-tiled LDS image per K-tile
//   gemm1_mfma6 : z1 = batch @ W1^T via 6-term exact-split MFMA (fp32 quality)
//   fused_scan  : scan1 + gemm2 + scan2 in one kernel (V1/z2 never touch HBM)
//
// ws layout: Wg (672000 B) | z1p (131072*100 f32)

#define FHN_DT 0.04f

typedef __attribute__((ext_vector_type(8))) short          bf16x8;
typedef __attribute__((ext_vector_type(4))) float          f32x4;
typedef __attribute__((ext_vector_type(8))) unsigned short ushort8;

__device__ __forceinline__ unsigned short f2bf(float x) {
    unsigned u = __float_as_uint(x);
    u += 0x7fffu + ((u >> 16) & 1u);      // RNE
    return (unsigned short)(u >> 16);
}
__device__ __forceinline__ float bf2f(unsigned short h) {
    return __uint_as_float(((unsigned)h) << 16);
}

// ---------------- prep: W1 (100x784) -> tiled 3-term split image ----------------
// Image: [kt=25][term=3][n=112][40 shorts (32 data + 8 pad)]  == per-tile LDS bytes
__global__ void prep_w6(const float* __restrict__ W1, unsigned short* __restrict__ Wg) {
    int idx = blockIdx.x * 256 + threadIdx.x;
    if (idx >= 336000) return;
    int sh    = idx % 40;
    int rest  = idx / 40;
    int n     = rest % 112;
    int rest2 = rest / 112;
    int term  = rest2 % 3;
    int kt    = rest2 / 3;
    int k = kt * 32 + sh;
    float v = (n < 100 && sh < 32 && k < 784) ? W1[n * 784 + k] : 0.0f;
    unsigned short h = f2bf(v);
    float r1 = v - bf2f(h);
    unsigned short m = f2bf(r1);
    float r2 = r1 - bf2f(m);
    unsigned short l = f2bf(r2);
    Wg[idx] = (term == 0) ? h : ((term == 1) ? m : l);
}

// ---------------- GEMM1: 6-term exact split, BM=128, BK=32, 4 waves ----------------
#define GA_H 0
#define GA_M 10240
#define GA_L 20480
#define GW   30720
#define GLDS (30720 + 26880)   // 57600 B

__device__ __forceinline__ void load_a_tile(const float* __restrict__ aptr, int kt, int ahalf,
                                            float4* areg) {
#pragma unroll
    for (int q = 0; q < 4; ++q) {
        int k = kt * 32 + ahalf * 16 + q * 4;
        if (k < 784) areg[q] = *(const float4*)(aptr + kt * 32 + q * 4);
        else         areg[q] = make_float4(0.f, 0.f, 0.f, 0.f);
    }
}

__device__ __forceinline__ void load_w_tile(const unsigned short* __restrict__ Wg, int kt, int tid,
                                            ushort8* wreg) {
#pragma unroll
    for (int j = 0; j < 7; ++j) {
        int off = j * 4096 + tid * 16;                 // bytes within 26880-B tile
        if (off < 26880) wreg[j] = *(const ushort8*)(Wg + (size_t)kt * 13440 + off / 2);
    }
}

__global__ __launch_bounds__(256, 2) void gemm1_mfma6(const float* __restrict__ A,
                                                      const unsigned short* __restrict__ Wg,
                                                      float* __restrict__ z1p) {
    __shared__ __align__(16) char smem[GLDS];
    const int tid  = threadIdx.x;
    const int w    = tid >> 6;
    const int lane = tid & 63;
    const long row0 = (long)blockIdx.x * 128;
    const int arow = tid >> 1, ahalf = tid & 1;
    const float* aptr = A + (row0 + arow) * 784 + ahalf * 16;

    float4  areg[4];
    ushort8 wreg[7];
    f32x4 acc[2][7] = {};

    load_a_tile(aptr, 0, ahalf, areg);
    load_w_tile(Wg, 0, tid, wreg);

    for (int kt = 0; kt < 25; ++kt) {
        // ---- store staged tile to LDS (convert A fp32 -> exact h/m/l bf16) ----
#pragma unroll
        for (int half8 = 0; half8 < 2; ++half8) {
            ushort8 hv, mv, lv;
#pragma unroll
            for (int q = 0; q < 2; ++q) {
                float4 v = areg[half8 * 2 + q];
#define SPLIT3(val, j) { float a_ = (val); unsigned short h_ = f2bf(a_); \
                         float r1_ = a_ - bf2f(h_); unsigned short m_ = f2bf(r1_); \
                         float r2_ = r1_ - bf2f(m_); \
                         hv[j] = (short)h_; mv[j] = (short)m_; lv[j] = (short)f2bf(r2_); }
                SPLIT3(v.x, q * 4 + 0)
                SPLIT3(v.y, q * 4 + 1)
                SPLIT3(v.z, q * 4 + 2)
                SPLIT3(v.w, q * 4 + 3)
#undef SPLIT3
            }
            char* da = smem + arow * 80 + ahalf * 32 + half8 * 16;
            *(ushort8*)(da + GA_H) = hv;
            *(ushort8*)(da + GA_M) = mv;
            *(ushort8*)(da + GA_L) = lv;
        }
#pragma unroll
        for (int j = 0; j < 7; ++j) {
            int off = j * 4096 + tid * 16;
            if (off < 26880) *(ushort8*)(smem + GW + off) = wreg[j];
        }
        // ---- prefetch next tile into regs (flies during compute) ----
        if (kt < 24) {
            load_a_tile(aptr, kt + 1, ahalf, areg);
            load_w_tile(Wg, kt + 1, tid, wreg);
        }
        __syncthreads();

        // ---- compute: 2 row-tiles x 7 col-tiles x 6 exact-split terms ----
        const int ln = lane & 15;
        const int kb = (lane >> 4) * 16;
        bf16x8 ah[2], am[2], al[2];
#pragma unroll
        for (int rt = 0; rt < 2; ++rt) {
            const char* pa = smem + (w * 32 + rt * 16 + ln) * 80 + kb;
            ah[rt] = *(const bf16x8*)(pa + GA_H);
            am[rt] = *(const bf16x8*)(pa + GA_M);
            al[rt] = *(const bf16x8*)(pa + GA_L);
        }
#pragma unroll
        for (int ct = 0; ct < 7; ++ct) {
            const char* pw = smem + GW + (ct * 16 + ln) * 80 + kb;
            bf16x8 bh = *(const bf16x8*)(pw);
            bf16x8 bm = *(const bf16x8*)(pw + 8960);
            bf16x8 bl = *(const bf16x8*)(pw + 17920);
#pragma unroll
            for (int rt = 0; rt < 2; ++rt) {
                f32x4 c = acc[rt][ct];
                c = __builtin_amdgcn_mfma_f32_16x16x32_bf16(ah[rt], bh, c, 0, 0, 0);
                c = __builtin_amdgcn_mfma_f32_16x16x32_bf16(ah[rt], bm, c, 0, 0, 0);
                c = __builtin_amdgcn_mfma_f32_16x16x32_bf16(am[rt], bh, c, 0, 0, 0);
                c = __builtin_amdgcn_mfma_f32_16x16x32_bf16(ah[rt], bl, c, 0, 0, 0);
                c = __builtin_amdgcn_mfma_f32_16x16x32_bf16(al[rt], bh, c, 0, 0, 0);
                c = __builtin_amdgcn_mfma_f32_16x16x32_bf16(am[rt], bm, c, 0, 0, 0);
                acc[rt][ct] = c;
            }
        }
        __syncthreads();
    }

    // ---- epilogue: C/D map col=lane&15, row=(lane>>4)*4+r ----
    const int ln = lane & 15, lg = lane >> 4;
#pragma unroll
    for (int ct = 0; ct < 7; ++ct) {
        int n = ct * 16 + ln;
        if (n < 100) {
#pragma unroll
            for (int rt = 0; rt < 2; ++rt) {
                long rg = row0 + w * 32 + rt * 16 + lg * 4;
                float* p = z1p + rg * 100 + n;
#pragma unroll
                for (int r = 0; r < 4; ++r) p[r * 100] = acc[rt][ct][r];
            }
        }
    }
}

// ---------------- fused scan1 + gemm2 + scan2 ----------------
// 64 blocks (one per batch b), 256 threads:
//   tid 0..99   : scan1 lanes (n = tid), chunk i
//   tid 100..109: scan2 lanes (m = tid-100), chunk i-2 (same SIMT FHN loop)
//   tid 128..255: gemm2 (chunk i-1, t = tid-128) + V2 copy-out (chunk i-3)
// LDS (floats): V1s[2][128][116] @0 (cols 0-99 = V1, 100-109 = V2)
//               z2s[2][128][12]  @29696
//               W2s[10][104]     @32768      total 33808 f = 132.1 KB
__global__ __launch_bounds__(256) void fused_scan(const float* __restrict__ z1p,
                                                  const float* __restrict__ W2,
                                                  float* __restrict__ out) {
    __shared__ float fsm[33808];
    const int tid = threadIdx.x;
    const int b = blockIdx.x;
    for (int i = tid; i < 1000; i += 256) fsm[32768 + (i / 100) * 104 + (i % 100)] = W2[i];

    const float dt = FHN_DT;
    float V = 0.f, S = 0.f;
    const float* zb = z1p + (long)b * 2048 * 100 + tid;   // used by tid<100 only
    float zc[16], zn[16];
    if (tid < 100) {
#pragma unroll
        for (int u = 0; u < 16; ++u) zc[u] = zb[u * 100];
    }
    __syncthreads();

    for (int i = 0; i <= 18; ++i) {
        if (tid < 128) {
            bool a1 = (tid < 100) && (i < 16);
            bool a2 = (tid >= 100) && (tid < 110) && (i >= 2) && (i < 18);
            if (a1 || a2) {
                const int cw = i & 1;
                for (int sub = 0; sub < 8; ++sub) {
                    if (a1) {
                        int tn = i * 128 + (sub + 1) * 16;
                        if (tn < 2048) {
#pragma unroll
                            for (int u = 0; u < 16; ++u) zn[u] = zb[(tn + u) * 100];
                        }
                    }
                    if (a2) {
#pragma unroll
                        for (int u = 0; u < 16; ++u)
                            zc[u] = fsm[29696 + cw * 1536 + (sub * 16 + u) * 12 + (tid - 100)];
                    }
#pragma unroll
                    for (int u = 0; u < 16; ++u) {
                        int tl = sub * 16 + u;
                        fsm[cw * 14848 + tl * 116 + tid] = V;
                        float z  = zc[u];
                        float V3 = V * V * V;
                        float Vn = fmaf(1.f + dt, V,
                                    fmaf(-dt / 3.f, V3, fmaf(-dt, S, dt * z)));
                        float Sn = fmaf(dt * 0.08f, V + 0.7f - 0.8f * S, S);
                        V = Vn; S = Sn;
                    }
                    if (a1) {
#pragma unroll
                        for (int u = 0; u < 16; ++u) zc[u] = zn[u];
                    }
                }
            }
        } else {
            const int tg = tid - 128;
            if (i >= 1 && i <= 16) {
                const int pb = (i - 1) & 1;
                float acc[10] = {0.f,0.f,0.f,0.f,0.f,0.f,0.f,0.f,0.f,0.f};
                for (int kq = 0; kq < 25; ++kq) {
                    float4 v = *(const float4*)&fsm[pb * 14848 + tg * 116 + kq * 4];
#pragma unroll
                    for (int m = 0; m < 10; ++m) {
                        float4 wv = *(const float4*)&fsm[32768 + m * 104 + kq * 4];
                        acc[m] = fmaf(v.x, wv.x, acc[m]);
                        acc[m] = fmaf(v.y, wv.y, acc[m]);
                        acc[m] = fmaf(v.z, wv.z, acc[m]);
                        acc[m] = fmaf(v.w, wv.w, acc[m]);
                    }
                }
#pragma unroll
                for (int m = 0; m < 10; ++m)
                    fsm[29696 + pb * 1536 + tg * 12 + m] = 0.5f * acc[m];
            }
            if (i >= 3) {
                const int pb = (i - 1) & 1;
                float* dst = out + ((long)b * 2048 + (long)(i - 3) * 128 + tg) * 10;
#pragma unroll
                for (int m = 0; m < 10; ++m) dst[m] = fsm[pb * 14848 + tg * 116 + 100 + m];
            }
        }
        __syncthreads();
    }
}

extern "C" void kernel_launch(void* const* d_in, const int* in_sizes, int n_in,
                              void* d_out, int out_size, void* d_ws, size_t ws_size,
                              hipStream_t stream) {
    const float* batch = (const float*)d_in[0];   // 64*2048*784
    const float* W1    = (const float*)d_in[1];   // 100*784
    const float* W2    = (const float*)d_in[2];   // 10*100
    float* out = (float*)d_out;                   // 64*2048*10

    char* base = (char*)d_ws;
    unsigned short* Wg = (unsigned short*)base;            // 672000 B
    float* z1p = (float*)(base + 672000);                  // 131072*100 f32

    prep_w6<<<1313, 256, 0, stream>>>(W1, Wg);
    gemm1_mfma6<<<1024, 256, 0, stream>>>(batch, Wg, z1p);
    fused_scan<<<64, 256, 0, stream>>>(z1p, W2, out);
}